// Round 1
// baseline (484.796 us; speedup 1.0000x reference)
//
#include <hip/hip_runtime.h>
#include <stdint.h>

#define MDIM 4096
#define NDIM 4096
#define KDIM 4096

typedef float f32x4 __attribute__((ext_vector_type(4)));
typedef __bf16 bf16x8 __attribute__((ext_vector_type(8)));
typedef short s16x8 __attribute__((ext_vector_type(8)));

__device__ __forceinline__ short f2bf(float x) {
  union { float f; unsigned u; } v; v.f = x;
  unsigned r = (v.u + 0x7fffu + ((v.u >> 16) & 1u)) >> 16;
  return (short)r;
}

// ---- 1. scatter COO -> dense W (fp32, atomic accumulate; duplicates add) ----
__global__ void scatter_kernel(const int* __restrict__ rows, const int* __restrict__ cols,
                               const float* __restrict__ vals, float* __restrict__ Wf, int nnz) {
  int i = blockIdx.x * blockDim.x + threadIdx.x;
  if (i < nnz) {
    atomicAdd(&Wf[rows[i] * KDIM + cols[i]], vals[i]);
  }
}

// ---- 2. convert W fp32 -> bf16 (row-major M x K, k-contiguous) ----
__global__ void convw_kernel(const float* __restrict__ Wf, short* __restrict__ Wb) {
  int i = (blockIdx.x * blockDim.x + threadIdx.x) * 8;
  f32x4 f0 = *(const f32x4*)(Wf + i);
  f32x4 f1 = *(const f32x4*)(Wf + i + 4);
  s16x8 s;
  s[0] = f2bf(f0[0]); s[1] = f2bf(f0[1]); s[2] = f2bf(f0[2]); s[3] = f2bf(f0[3]);
  s[4] = f2bf(f1[0]); s[5] = f2bf(f1[1]); s[6] = f2bf(f1[2]); s[7] = f2bf(f1[3]);
  *(s16x8*)(Wb + i) = s;
}

// ---- 3. transpose+convert x (K x N fp32) -> xT (N x K bf16, k-contiguous) ----
__global__ void transx_kernel(const float* __restrict__ x, short* __restrict__ xT) {
  __shared__ float tile[32][33];  // +1 pad: conflict-free transpose
  int n0 = blockIdx.x * 32, k0 = blockIdx.y * 32;
  int tx = threadIdx.x, ty = threadIdx.y;  // block (32, 8)
#pragma unroll
  for (int j = 0; j < 32; j += 8)
    tile[ty + j][tx] = x[(k0 + ty + j) * NDIM + n0 + tx];
  __syncthreads();
#pragma unroll
  for (int j = 0; j < 32; j += 8)
    xT[(n0 + ty + j) * KDIM + k0 + tx] = f2bf(tile[tx][ty + j]);
}

// ---- 4. bf16 MFMA GEMM: C[m][n] = sum_k A[m][k]*B[n][k]^T + bias[n] ----
// A = Wb (M x K row-major), Bt = xT (N x K row-major). 128x128 block tile,
// BK=32, 4 waves, each wave 64x64 (4x4 tiles of 16x16x32 MFMA).
// LDS layout is fragment-ordered: 16B chunk index = tile*64 + (q*16 + e16),
// so global_load_lds (wave-uniform base + lane*16) and ds_read_b128 fragment
// reads are both fully lane-contiguous (conflict-free).
__global__ __launch_bounds__(256) void gemm_kernel(const short* __restrict__ A,
                                                   const short* __restrict__ Bt,
                                                   const float* __restrict__ bias,
                                                   float* __restrict__ C) {
  __shared__ __align__(16) short sA[128 * 32];
  __shared__ __align__(16) short sB[128 * 32];
  int tid = threadIdx.x;
  int lane = tid & 63, wave = tid >> 6;
  int wr = wave >> 1, wc = wave & 1;
  int m16 = lane & 15, quad = lane >> 4;
  int rowBase = blockIdx.y * 128;
  int colBase = blockIdx.x * 128;

  f32x4 acc[4][4];
#pragma unroll
  for (int i = 0; i < 4; i++)
#pragma unroll
    for (int j = 0; j < 4; j++)
      acc[i][j] = f32x4{0.f, 0.f, 0.f, 0.f};

  // Per-thread staging coordinates: chunk c = it*256 + tid covers 8 shorts
  // (element row t*16+(l&15), k-offset q*8) with t=c>>6, l=c&63, q=l>>4.
  int aOff[2], bOff[2];
#pragma unroll
  for (int it = 0; it < 2; it++) {
    int c = it * 256 + tid;
    int t = c >> 6, l = c & 63;
    int e = t * 16 + (l & 15);
    int q = l >> 4;
    aOff[it] = (rowBase + e) * KDIM + q * 8;
    bOff[it] = (colBase + e) * KDIM + q * 8;
  }

  for (int k0 = 0; k0 < KDIM; k0 += 32) {
#pragma unroll
    for (int it = 0; it < 2; it++) {
      const short* ga = A + aOff[it] + k0;
      const short* gb = Bt + bOff[it] + k0;
      __builtin_amdgcn_global_load_lds(
          (const __attribute__((address_space(1))) void*)ga,
          (__attribute__((address_space(3))) void*)&sA[(it * 256 + wave * 64) * 8], 16, 0, 0);
      __builtin_amdgcn_global_load_lds(
          (const __attribute__((address_space(1))) void*)gb,
          (__attribute__((address_space(3))) void*)&sB[(it * 256 + wave * 64) * 8], 16, 0, 0);
    }
    __syncthreads();

    bf16x8 a[4], b[4];
#pragma unroll
    for (int i = 0; i < 4; i++)
      a[i] = *(const bf16x8*)&sA[((wr * 4 + i) * 64 + lane) * 8];
#pragma unroll
    for (int j = 0; j < 4; j++)
      b[j] = *(const bf16x8*)&sB[((wc * 4 + j) * 64 + lane) * 8];
#pragma unroll
    for (int i = 0; i < 4; i++)
#pragma unroll
      for (int j = 0; j < 4; j++)
        acc[i][j] = __builtin_amdgcn_mfma_f32_16x16x32_bf16(a[i], b[j], acc[i][j], 0, 0, 0);
    __syncthreads();
  }

  // Epilogue: C/D layout col = lane&15, row = quad*4 + reg
#pragma unroll
  for (int j = 0; j < 4; j++) {
    int col = colBase + wc * 64 + j * 16 + m16;
    float bv = bias[col];
#pragma unroll
    for (int i = 0; i < 4; i++) {
      int row0 = rowBase + wr * 64 + i * 16 + quad * 4;
      f32x4 v = acc[i][j];
#pragma unroll
      for (int r = 0; r < 4; r++)
        C[(row0 + r) * NDIM + col] = v[r] + bv;
    }
  }
}

extern "C" void kernel_launch(void* const* d_in, const int* in_sizes, int n_in,
                              void* d_out, int out_size, void* d_ws, size_t ws_size,
                              hipStream_t stream) {
  const float* x = (const float*)d_in[0];
  const int* rows = (const int*)d_in[1];
  const int* cols = (const int*)d_in[2];
  const float* vals = (const float*)d_in[3];
  const float* bias = (const float*)d_in[4];
  int nnz = in_sizes[1];
  float* y = (float*)d_out;

  // ws layout: [0,64MB) Wf32; [64MB,96MB) Wbf16; xT reuses [0,32MB) after convw
  float* Wf = (float*)d_ws;
  short* Wb = (short*)((char*)d_ws + (64u << 20));
  short* xT = (short*)d_ws;

  hipMemsetAsync(Wf, 0, (size_t)MDIM * KDIM * sizeof(float), stream);
  scatter_kernel<<<(nnz + 255) / 256, 256, 0, stream>>>(rows, cols, vals, Wf, nnz);
  convw_kernel<<<(MDIM * KDIM / 8) / 256, 256, 0, stream>>>(Wf, Wb);
  transx_kernel<<<dim3(NDIM / 32, KDIM / 32), dim3(32, 8), 0, stream>>>(x, xT);
  gemm_kernel<<<dim3(NDIM / 128, MDIM / 128), 256, 0, stream>>>(Wb, xT, bias, y);
}

// Round 2
// 465.728 us; speedup vs baseline: 1.0409x; 1.0409x over previous
//
#include <hip/hip_runtime.h>
#include <stdint.h>

#define MDIM 4096
#define NDIM 4096
#define KDIM 4096

typedef float f32x4 __attribute__((ext_vector_type(4)));
typedef __bf16 bf16x8 __attribute__((ext_vector_type(8)));

__device__ __forceinline__ unsigned short f2bf(float x) {
  union { float f; unsigned u; } v; v.f = x;
  return (unsigned short)((v.u + 0x7fffu + ((v.u >> 16) & 1u)) >> 16);
}
__device__ __forceinline__ float bf2f(unsigned short b) {
  union { unsigned u; float f; } v; v.u = ((unsigned)b) << 16;
  return v.f;
}

// ---- 1. scatter COO directly into bf16 W (CAS accumulate; duplicates add) ----
__global__ void scatter_kernel(const int* __restrict__ rows, const int* __restrict__ cols,
                               const float* __restrict__ vals, unsigned* __restrict__ Wb,
                               int nnz) {
  int i = blockIdx.x * blockDim.x + threadIdx.x;
  if (i >= nnz) return;
  int r = rows[i], c = cols[i];
  float v = vals[i];
  unsigned* word = &Wb[((size_t)r * KDIM + c) >> 1];
  unsigned shift = (c & 1) ? 16u : 0u;
  unsigned old = *word, assumed;
  do {
    assumed = old;
    unsigned short cur = (unsigned short)(assumed >> shift);
    unsigned short upd = f2bf(bf2f(cur) + v);
    unsigned next = (assumed & ~(0xffffu << shift)) | ((unsigned)upd << shift);
    if (next == assumed) break;  // no bit change; done
    old = atomicCAS(word, assumed, next);
  } while (old != assumed);
}

// ---- 2. transpose+convert x (K x N fp32) -> xT (N x K bf16, k-contiguous) ----
__global__ void transx_kernel(const float* __restrict__ x, short* __restrict__ xT) {
  __shared__ float tile[32][33];  // +1 pad: conflict-free transpose
  int n0 = blockIdx.x * 32, k0 = blockIdx.y * 32;
  int tx = threadIdx.x, ty = threadIdx.y;  // block (32, 8)
#pragma unroll
  for (int j = 0; j < 32; j += 8)
    tile[ty + j][tx] = x[(k0 + ty + j) * NDIM + n0 + tx];
  __syncthreads();
#pragma unroll
  for (int j = 0; j < 32; j += 8)
    xT[(n0 + ty + j) * KDIM + k0 + tx] = (short)f2bf(tile[tx][ty + j]);
}

// ---- 3. bf16 MFMA GEMM: C[m][n] = sum_k A[m][k]*Bt[n][k] + bias[n] ----
// 128x128 block tile, BK=64 (2 k-halves of 32), 4 waves, each wave 64x64
// (4x4 tiles of 16x16x32 MFMA). LDS is fragment-ordered: fragment f = t*2+h
// (t = 16-row tile 0..7, h = k-half 0..1) occupies 64 contiguous 16B chunks,
// chunk = lane. global_load_lds (wave-uniform base + lane*16) and
// ds_read_b128 fragment reads are both lane-contiguous (conflict-free).
__global__ __launch_bounds__(256) void gemm_kernel(const short* __restrict__ A,
                                                   const short* __restrict__ Bt,
                                                   const float* __restrict__ bias,
                                                   float* __restrict__ C) {
  __shared__ __align__(16) short sA[128 * 64];
  __shared__ __align__(16) short sB[128 * 64];
  int tid = threadIdx.x;
  int lane = tid & 63, wave = tid >> 6;
  int wr = wave >> 1, wc = wave & 1;
  int m16 = lane & 15, quad = lane >> 4;
  int rowBase = blockIdx.y * 128;
  int colBase = blockIdx.x * 128;

  f32x4 acc[4][4];
#pragma unroll
  for (int i = 0; i < 4; i++)
#pragma unroll
    for (int j = 0; j < 4; j++)
      acc[i][j] = f32x4{0.f, 0.f, 0.f, 0.f};

  // Staging: iteration it stages fragment f = it*4 + wave; this lane's 16B
  // chunk holds global (row = t*16 + (lane&15), k = h*32 + quad*8 .. +8).
  int aOff[4], bOff[4], ldsOff[4];
#pragma unroll
  for (int it = 0; it < 4; it++) {
    int f = it * 4 + wave;
    int t = f >> 1, h = f & 1;
    int row = t * 16 + m16;
    int koff = h * 32 + quad * 8;
    aOff[it] = (rowBase + row) * KDIM + koff;
    bOff[it] = (colBase + row) * KDIM + koff;
    ldsOff[it] = f * 64 * 8;  // shorts; HW adds lane*16B
  }

  for (int k0 = 0; k0 < KDIM; k0 += 64) {
#pragma unroll
    for (int it = 0; it < 4; it++) {
      __builtin_amdgcn_global_load_lds(
          (const __attribute__((address_space(1))) void*)(A + aOff[it] + k0),
          (__attribute__((address_space(3))) void*)&sA[ldsOff[it]], 16, 0, 0);
      __builtin_amdgcn_global_load_lds(
          (const __attribute__((address_space(1))) void*)(Bt + bOff[it] + k0),
          (__attribute__((address_space(3))) void*)&sB[ldsOff[it]], 16, 0, 0);
    }
    __syncthreads();

#pragma unroll
    for (int h = 0; h < 2; h++) {
      bf16x8 a[4], b[4];
#pragma unroll
      for (int i = 0; i < 4; i++)
        a[i] = *(const bf16x8*)&sA[(((wr * 4 + i) * 2 + h) * 64 + lane) * 8];
#pragma unroll
      for (int j = 0; j < 4; j++)
        b[j] = *(const bf16x8*)&sB[(((wc * 4 + j) * 2 + h) * 64 + lane) * 8];
#pragma unroll
      for (int i = 0; i < 4; i++)
#pragma unroll
        for (int j = 0; j < 4; j++)
          acc[i][j] = __builtin_amdgcn_mfma_f32_16x16x32_bf16(a[i], b[j], acc[i][j], 0, 0, 0);
    }
    __syncthreads();
  }

  // Epilogue: C/D layout col = lane&15, row = quad*4 + reg
#pragma unroll
  for (int j = 0; j < 4; j++) {
    int col = colBase + wc * 64 + j * 16 + m16;
    float bv = bias[col];
#pragma unroll
    for (int i = 0; i < 4; i++) {
      int row0 = rowBase + wr * 64 + i * 16 + quad * 4;
      f32x4 v = acc[i][j];
#pragma unroll
      for (int r = 0; r < 4; r++)
        C[(row0 + r) * NDIM + col] = v[r] + bv;
    }
  }
}

extern "C" void kernel_launch(void* const* d_in, const int* in_sizes, int n_in,
                              void* d_out, int out_size, void* d_ws, size_t ws_size,
                              hipStream_t stream) {
  const float* x = (const float*)d_in[0];
  const int* rows = (const int*)d_in[1];
  const int* cols = (const int*)d_in[2];
  const float* vals = (const float*)d_in[3];
  const float* bias = (const float*)d_in[4];
  int nnz = in_sizes[1];
  float* y = (float*)d_out;

  // ws layout: [0,32MB) W bf16; [32MB,64MB) xT bf16
  short* Wb = (short*)d_ws;
  short* xT = (short*)((char*)d_ws + (32u << 20));

  hipMemsetAsync(Wb, 0, (size_t)MDIM * KDIM * sizeof(short), stream);
  scatter_kernel<<<(nnz + 255) / 256, 256, 0, stream>>>(rows, cols, vals, (unsigned*)Wb, nnz);
  transx_kernel<<<dim3(NDIM / 32, KDIM / 32), dim3(32, 8), 0, stream>>>(x, xT);
  gemm_kernel<<<dim3(NDIM / 128, MDIM / 128), 256, 0, stream>>>(Wb, xT, bias, y);
}